// Round 1
// baseline (34.059 us; speedup 1.0000x reference)
//
#include <hip/hip_runtime.h>
#include <math.h>

// JPEG differentiable-codec fused kernel.
// Key identity: IDCT(DCT(p) + noise_f) = p + IDCT(noise_f)   (exact, linear)
// so we only IDCT the quantization noise: noise_f = table*AA*0.5*eps*rv, and
// the 0.25 IDCT prefactor folds in => t = 0.125*eps*table*AA*rv.
//
// Layout notes (from the reference's transposes):
//  - img[b,i,j,c] = pixel_inp[b,c,j,i]  (i = W index, j = H index)
//  - Y patch n = (i/8)*32 + (j/8), in-patch (x,y) = (i%8, j%8)
//  - chroma (128x128): n = (ci/8)*16 + (cj/8), ci=i/2, cj=j/2
//  - tables in reference are base.T, so table[x][y] = base[y][x]
//  - output[b,c,j,i] at same flat offset as input pixel.

__constant__ float YB[64] = {     // standard orientation; index [y*8+x] for table[x][y]
  16,11,10,16,24,40,51,61,
  12,12,14,19,26,58,60,55,
  14,13,16,24,40,57,69,56,
  14,17,22,29,51,87,80,62,
  18,22,37,56,68,109,103,77,
  24,35,55,64,81,104,113,92,
  49,64,78,87,103,121,120,101,
  72,92,95,98,112,100,103,99};

__constant__ float CBT[64] = {    // symmetric, transpose irrelevant
  17,18,24,47,99,99,99,99,
  18,21,26,66,99,99,99,99,
  24,26,56,99,99,99,99,99,
  47,66,99,99,99,99,99,99,
  99,99,99,99,99,99,99,99,
  99,99,99,99,99,99,99,99,
  99,99,99,99,99,99,99,99,
  99,99,99,99,99,99,99,99};

__global__ __launch_bounds__(256) void jpeg_kernel(
    const float* __restrict__ pix,   // [B,3,256,256]
    const float* __restrict__ rvy,   // [B,1024,8,8]
    const float* __restrict__ rvcb,  // [B,256,8,8]
    const float* __restrict__ rvcr,  // [B,256,8,8]
    const float* __restrict__ epsv,  // [B]
    float* __restrict__ out)         // [B,3,256,256]
{
    __shared__ float tY[4][64];      // scaled freq-noise, 4 Y blocks
    __shared__ float tC[2][64];      // cb, cr
    __shared__ float ctl[64];        // ctl[x*8+u] = cos((2u+1)*x*pi/16)
    __shared__ float nylds[16][16];  // Y noise, [dj][di]
    __shared__ float cpl[2][64];     // chroma pooled (+noise-128), [ci*8+cj]

    const int tid  = threadIdx.x;
    const int b    = blockIdx.y;
    const int ti   = blockIdx.x >> 4;   // tile i (W dir)
    const int tj   = blockIdx.x & 15;   // tile j (H dir)
    const int di   = tid & 15;
    const int dj   = tid >> 4;
    const int wave = tid >> 6;          // 0..3, == Y block id
    const int lane = tid & 63;
    const int fx   = lane >> 3;
    const int fy   = lane & 7;

    const float eps = epsv[b] * 0.125f;   // 0.25 (idct) * 0.5 (noisy_round)

    if (tid < 64) {
        // ctl[x*8+u], x=tid>>3, u=tid&7 : cos((2u+1)*x*pi/16)
        ctl[tid] = cosf((float)((2*fy + 1) * fx) * 0.19634954084936207f);
    }

    // ---- phase A: pixel load, RGB->YCC, chroma 2x2 pool via shuffles ----
    const int i = ti*16 + di;
    const int j = tj*16 + dj;
    const size_t pbase = (size_t)b*196608 + (size_t)j*256 + (size_t)i;
    const float r  = pix[pbase];
    const float g  = pix[pbase + 65536];
    const float bb = pix[pbase + 131072];
    const float yv  =  0.299f   *r + 0.587f   *g + 0.114f   *bb;
    const float cbv = -0.168736f*r - 0.331264f*g + 0.5f     *bb + 128.0f;
    const float crv =  0.5f     *r - 0.418688f*g - 0.081312f*bb + 128.0f;

    // 2x2 avg pool: di pair = lane^1, dj pair = lane^16 (both within wave64)
    float cbs = cbv + __shfl_xor(cbv, 1);
    cbs += __shfl_xor(cbs, 16);
    float crs = crv + __shfl_xor(crv, 1);
    crs += __shfl_xor(crs, 16);
    if (((di | dj) & 1) == 0) {
        const int ci = di >> 1, cj = dj >> 1;
        cpl[0][ci*8 + cj] = 0.25f * cbs;
        cpl[1][ci*8 + cj] = 0.25f * crs;
    }

    // ---- phase B: rv loads, scale into freq-noise t ----
    const float ax = (fx == 0) ? 0.70710678118654752f : 1.0f;
    const float ay = (fy == 0) ? 0.70710678118654752f : 1.0f;
    const float aaxy = ax * ay * eps;
    {
        const int bx = wave >> 1, by = wave & 1;
        const int n = (ti*2 + bx)*32 + (tj*2 + by);
        tY[wave][lane] = rvy[((size_t)b*1024 + n)*64 + lane] * (YB[fy*8 + fx] * aaxy);
    }
    if (wave < 2) {
        const int n = ti*16 + tj;
        const float* rvc = (wave == 0) ? rvcb : rvcr;
        tC[wave][lane] = rvc[((size_t)b*256 + n)*64 + lane] * (CBT[fy*8 + fx] * aaxy);
    }
    __syncthreads();

    // ---- phase C: separable 8x8 IDCT of noise ----
    {
        const int u = fx, v = fy;
        float acc = 0.0f;
        #pragma unroll
        for (int x = 0; x < 8; ++x) {
            float s = 0.0f;
            #pragma unroll
            for (int yy = 0; yy < 8; ++yy)
                s = fmaf(tY[wave][x*8 + yy], ctl[yy*8 + v], s);
            acc = fmaf(s, ctl[x*8 + u], acc);
        }
        const int bx = wave >> 1, by = wave & 1;
        nylds[by*8 + v][bx*8 + u] = acc;
    }
    if (wave < 2) {
        const int u = fx, v = fy;
        float acc = 0.0f;
        #pragma unroll
        for (int x = 0; x < 8; ++x) {
            float s = 0.0f;
            #pragma unroll
            for (int yy = 0; yy < 8; ++yy)
                s = fmaf(tC[wave][x*8 + yy], ctl[yy*8 + v], s);
            acc = fmaf(s, ctl[x*8 + u], acc);
        }
        cpl[wave][u*8 + v] += acc - 128.0f;   // pooled + noise - 128 (center)
    }
    __syncthreads();

    // ---- phase D: recombine, YCC->RGB, clip, store ----
    const float yf  = yv + nylds[dj][di];
    const int ci = di >> 1, cj = dj >> 1;
    const float cbf = cpl[0][ci*8 + cj];
    const float crf = cpl[1][ci*8 + cj];
    float ro = yf + 1.402f*crf;
    float go = yf - 0.344136f*cbf - 0.714136f*crf;
    float bo = yf + 1.772f*cbf;
    ro = fminf(fmaxf(ro, 0.0f), 255.0f);
    go = fminf(fmaxf(go, 0.0f), 255.0f);
    bo = fminf(fmaxf(bo, 0.0f), 255.0f);
    out[pbase]          = ro;
    out[pbase + 65536]  = go;
    out[pbase + 131072] = bo;
}

extern "C" void kernel_launch(void* const* d_in, const int* in_sizes, int n_in,
                              void* d_out, int out_size, void* d_ws, size_t ws_size,
                              hipStream_t stream) {
    const float* pix  = (const float*)d_in[0];
    const float* rvy  = (const float*)d_in[1];
    const float* rvcb = (const float*)d_in[2];
    const float* rvcr = (const float*)d_in[3];
    const float* eps  = (const float*)d_in[4];
    const int B = in_sizes[4];           // epsilon has one entry per batch
    dim3 grid(256, B);                   // 16x16 tiles over 256x256, per batch
    jpeg_kernel<<<grid, 256, 0, stream>>>(pix, rvy, rvcb, rvcr, eps, (float*)d_out);
}

// Round 2
// 25.267 us; speedup vs baseline: 1.3479x; 1.3479x over previous
//
#include <hip/hip_runtime.h>
#include <math.h>

// JPEG differentiable codec, fused. Identity: IDCT(DCT(p)+nf) = p + IDCT(nf),
// so only the quantization NOISE is IDCT'd: nf = 0.125*eps*table*AA*rv.
// Round-1 restructure: 32x32-pixel tile per block (256 thr), 4 px/thread via
// float4; separable two-stage 8x8 IDCT through LDS (16 FMA/px instead of 72).
//
// Index map (validated round 0): img[b,i,j,c] = pixel_inp[b,c,j,i];
// Y block n = (i/8)*32 + j/8, in-block (x,y) = (i%8, j%8); tables are .T so
// table[x][y] = std[y][x]; chroma at (i/2, j/2), blocks n=(ci/8)*16+cj/8.

__constant__ float YB[64] = {     // standard orientation; index [y*8+x]
  16,11,10,16,24,40,51,61,
  12,12,14,19,26,58,60,55,
  14,13,16,24,40,57,69,56,
  14,17,22,29,51,87,80,62,
  18,22,37,56,68,109,103,77,
  24,35,55,64,81,104,113,92,
  49,64,78,87,103,121,120,101,
  72,92,95,98,112,100,103,99};

__constant__ float CBT[64] = {
  17,18,24,47,99,99,99,99,
  18,21,26,66,99,99,99,99,
  24,26,56,99,99,99,99,99,
  47,66,99,99,99,99,99,99,
  99,99,99,99,99,99,99,99,
  99,99,99,99,99,99,99,99,
  99,99,99,99,99,99,99,99,
  99,99,99,99,99,99,99,99};

__global__ __launch_bounds__(256) void jpeg_kernel(
    const float* __restrict__ pix,   // [B,3,256,256]
    const float* __restrict__ rvy,   // [B,1024,8,8]
    const float* __restrict__ rvcb,  // [B,256,8,8]
    const float* __restrict__ rvcr,  // [B,256,8,8]
    const float* __restrict__ epsv,  // [B]
    float* __restrict__ out)         // [B,3,256,256]
{
    __shared__ float ctl[64];        // ctl[x*8+u] = cos((2u+1)x*pi/16)
    __shared__ float sclY[64];       // eps-folded freq scale, idx x*8+y
    __shared__ float sclC[64];
    __shared__ float tYf[1024];      // 16 Y blocks of scaled freq noise
    __shared__ float tCf[512];       // 4 Cb + 4 Cr blocks
    __shared__ float sY[1056];       // stage-1 out, [n][x][v], stride 66
    __shared__ float sC[528];
    __shared__ float pool[2][256];   // pooled chroma [c][cj*16+ci] -> +noise-128

    const int tid  = threadIdx.x;
    const int wave = tid >> 6;
    const int lane = tid & 63;
    const int b    = blockIdx.y;
    const int ti   = blockIdx.x >> 3;   // tile i (W dir), 32 px
    const int tj   = blockIdx.x & 7;    // tile j (H dir)
    const int qi   = tid & 7;           // i-quad: pixels i0..i0+3
    const int dj   = tid >> 3;          // j row 0..31

    const float eps8 = epsv[b] * 0.125f;   // 0.25(idct) * 0.5(noisy_round)

    if (tid < 64) {
        const int x = tid >> 3, y = tid & 7;
        ctl[tid] = cosf((float)((2*y + 1) * x) * 0.19634954084936207f);
        const float aa = ((x==0)?0.70710678118654752f:1.0f)
                       * ((y==0)?0.70710678118654752f:1.0f) * eps8;
        sclY[tid] = YB[y*8 + x] * aa;
        sclC[tid] = CBT[y*8 + x] * aa;
    }

    // ---- phase A: pixel float4 loads, RGB->YCC, chroma 2x2 pool ----
    const int i0 = ti*32 + qi*4;
    const int j  = tj*32 + dj;
    const size_t pb = (size_t)b*196608 + (size_t)j*256 + (size_t)i0;
    const float4 r4 = *(const float4*)(pix + pb);
    const float4 g4 = *(const float4*)(pix + pb + 65536);
    const float4 b4 = *(const float4*)(pix + pb + 131072);

    // rv loads issued early (consumed after barrier)
    const size_t rybase = ((size_t)b*1024 + (size_t)((ti*4 + wave)*32 + tj*4)) * 64;
    const float4 rv4 = *(const float4*)(rvy + rybase + (size_t)lane*4);

    const int cch = tid >> 7;           // 0=Cb 1=Cr
    const int run = (tid >> 6) & 1;     // chroma bx
    const int l2  = tid & 63;
    const float* __restrict__ rvc = cch ? rvcr : rvcb;
    const size_t rcbase = ((size_t)b*256 + (size_t)((ti*2 + run)*16 + tj*2)) * 64;
    const float2 rc2 = *(const float2*)(rvc + rcbase + (size_t)l2*2);

    const float rr[4] = {r4.x, r4.y, r4.z, r4.w};
    const float gg[4] = {g4.x, g4.y, g4.z, g4.w};
    const float bp[4] = {b4.x, b4.y, b4.z, b4.w};
    float yv[4], cbv[4], crv[4];
    #pragma unroll
    for (int c = 0; c < 4; ++c) {
        yv[c]  =  0.299f*rr[c] + 0.587f*gg[c] + 0.114f*bp[c];
        cbv[c] = -0.168736f*rr[c] - 0.331264f*gg[c] + 0.5f*bp[c] + 128.0f;
        crv[c] =  0.5f*rr[c] - 0.418688f*gg[c] - 0.081312f*bp[c] + 128.0f;
    }
    float cb01 = cbv[0]+cbv[1], cb23 = cbv[2]+cbv[3];
    float cr01 = crv[0]+crv[1], cr23 = crv[2]+crv[3];
    cb01 += __shfl_xor(cb01, 8);     // partner row j^1 (dj bit0 = lane bit3)
    cb23 += __shfl_xor(cb23, 8);
    cr01 += __shfl_xor(cr01, 8);
    cr23 += __shfl_xor(cr23, 8);
    if ((dj & 1) == 0) {
        const int cj = dj >> 1;
        const int ci0 = qi*2;
        *(float2*)&pool[0][cj*16 + ci0] = make_float2(0.25f*cb01, 0.25f*cb23);
        *(float2*)&pool[1][cj*16 + ci0] = make_float2(0.25f*cr01, 0.25f*cr23);
    }
    __syncthreads();   // consts (ctl/scl) ready

    // ---- staging: scale rv into LDS (linear layouts) ----
    {
        const int o = (lane*4) & 63;                 // in-block offset, x=o>>3
        const float4 s4 = *(const float4*)&sclY[o];
        float4 t;
        t.x = rv4.x*s4.x; t.y = rv4.y*s4.y; t.z = rv4.z*s4.z; t.w = rv4.w*s4.w;
        *(float4*)&tYf[tid*4] = t;
    }
    {
        const int o = (l2*2) & 63;
        const float2 s2 = *(const float2*)&sclC[o];
        *(float2*)&tCf[tid*2] = make_float2(rc2.x*s2.x, rc2.y*s2.y);
    }
    __syncthreads();

    // ---- stage 1: contract y with ctl[y][v]  -> s[n][x][v] (stride 66) ----
    const int x8 = (lane >> 3) * 8;
    const int v  = lane & 7;
    float cv[8];
    #pragma unroll
    for (int y = 0; y < 8; ++y) cv[y] = ctl[y*8 + v];
    #pragma unroll
    for (int k = 0; k < 4; ++k) {
        const int n = k*4 + wave;
        const float4 a0 = *(const float4*)&tYf[n*64 + x8];
        const float4 a1 = *(const float4*)&tYf[n*64 + x8 + 4];
        float acc = a0.x*cv[0];
        acc = fmaf(a0.y, cv[1], acc);
        acc = fmaf(a0.z, cv[2], acc);
        acc = fmaf(a0.w, cv[3], acc);
        acc = fmaf(a1.x, cv[4], acc);
        acc = fmaf(a1.y, cv[5], acc);
        acc = fmaf(a1.z, cv[6], acc);
        acc = fmaf(a1.w, cv[7], acc);
        sY[n*66 + x8 + v] = acc;
    }
    #pragma unroll
    for (int k = 0; k < 2; ++k) {
        const int n = k*4 + wave;                    // n = cch*4 + n_c
        const float4 a0 = *(const float4*)&tCf[n*64 + x8];
        const float4 a1 = *(const float4*)&tCf[n*64 + x8 + 4];
        float acc = a0.x*cv[0];
        acc = fmaf(a0.y, cv[1], acc);
        acc = fmaf(a0.z, cv[2], acc);
        acc = fmaf(a0.w, cv[3], acc);
        acc = fmaf(a1.x, cv[4], acc);
        acc = fmaf(a1.y, cv[5], acc);
        acc = fmaf(a1.z, cv[6], acc);
        acc = fmaf(a1.w, cv[7], acc);
        sC[n*66 + x8 + v] = acc;
    }
    __syncthreads();

    // ---- stage 2 Y: contract x with ctl[x][u], 4 pixels in registers ----
    float yn[4];
    {
        const int u0 = (qi & 1) * 4;
        const int nb = ((qi >> 1)*4 + wave)*66 + (lane >> 3);  // n*66 + v
        float a0=0.f, a1=0.f, a2=0.f, a3=0.f;
        #pragma unroll
        for (int x = 0; x < 8; ++x) {
            const float sv = sY[nb + x*8];
            a0 = fmaf(sv, ctl[x*8 + u0 + 0], a0);
            a1 = fmaf(sv, ctl[x*8 + u0 + 1], a1);
            a2 = fmaf(sv, ctl[x*8 + u0 + 2], a2);
            a3 = fmaf(sv, ctl[x*8 + u0 + 3], a3);
        }
        yn[0]=a0; yn[1]=a1; yn[2]=a2; yn[3]=a3;
    }
    // ---- chroma stage 2 + combine into pool (in place) ----
    {
        const int ci = tid & 15, cjc = tid >> 4;
        const int uC = ci & 7, vC = cjc & 7;
        const int nc = (ci >> 3)*2 + (cjc >> 3);
        #pragma unroll
        for (int k = 0; k < 2; ++k) {
            const int base = (k*4 + nc)*66 + vC;
            float acc = -128.0f;
            #pragma unroll
            for (int x = 0; x < 8; ++x)
                acc = fmaf(sC[base + x*8], ctl[x*8 + uC], acc);
            pool[k][cjc*16 + ci] += acc;   // pooled + noise - 128
        }
    }
    __syncthreads();

    // ---- final: recombine, YCC->RGB, clip, float4 stores ----
    const int cjf = dj >> 1;
    float ro[4], go[4], bo[4];
    #pragma unroll
    for (int c = 0; c < 4; ++c) {
        const int ci = qi*2 + (c >> 1);
        const float yf  = yv[c] + yn[c];
        const float cbf = pool[0][cjf*16 + ci];
        const float crf = pool[1][cjf*16 + ci];
        float r_ = fmaf(1.402f, crf, yf);
        float g_ = yf - 0.344136f*cbf - 0.714136f*crf;
        float b_ = fmaf(1.772f, cbf, yf);
        ro[c] = fminf(fmaxf(r_, 0.0f), 255.0f);
        go[c] = fminf(fmaxf(g_, 0.0f), 255.0f);
        bo[c] = fminf(fmaxf(b_, 0.0f), 255.0f);
    }
    *(float4*)(out + pb)          = make_float4(ro[0], ro[1], ro[2], ro[3]);
    *(float4*)(out + pb + 65536)  = make_float4(go[0], go[1], go[2], go[3]);
    *(float4*)(out + pb + 131072) = make_float4(bo[0], bo[1], bo[2], bo[3]);
}

extern "C" void kernel_launch(void* const* d_in, const int* in_sizes, int n_in,
                              void* d_out, int out_size, void* d_ws, size_t ws_size,
                              hipStream_t stream) {
    const float* pix  = (const float*)d_in[0];
    const float* rvy  = (const float*)d_in[1];
    const float* rvcb = (const float*)d_in[2];
    const float* rvcr = (const float*)d_in[3];
    const float* eps  = (const float*)d_in[4];
    const int B = in_sizes[4];           // epsilon: one per batch
    dim3 grid(64, B);                    // 8x8 tiles of 32x32 px, per batch
    jpeg_kernel<<<grid, 256, 0, stream>>>(pix, rvy, rvcb, rvcr, eps, (float*)d_out);
}